// Round 1
// baseline (221.203 us; speedup 1.0000x reference)
//
#include <hip/hip_runtime.h>
#include <hip/hip_bf16.h>

typedef float f32x4 __attribute__((ext_vector_type(4)));
typedef short bf16x8 __attribute__((ext_vector_type(8)));
typedef unsigned int u32x2 __attribute__((ext_vector_type(2)));

#define TILE_ROWS 64
#define LDS_STRIDE 136   // ushorts per LDS row (272 B = 16B-aligned, non-pow2 -> <=2-way bank alias, free)

__device__ __forceinline__ unsigned short f2bf(float f) {
    union { float f; unsigned int u; } v; v.f = f;
    unsigned int u = v.u;
    u += 0x7FFFu + ((u >> 16) & 1u);   // round-to-nearest-even
    return (unsigned short)(u >> 16);
}

// w_eff[o][h] = (w1[o][h] + w2[o][h]) * weight[h], bf16, row-major [128][128]
__global__ void prep_weights_kernel(const float* __restrict__ w1,
                                    const float* __restrict__ w2,
                                    const float* __restrict__ weight,
                                    unsigned short* __restrict__ weff) {
    int idx = blockIdx.x * 256 + threadIdx.x;   // 64 blocks * 256 = 16384
    int h = idx & 127;
    weff[idx] = f2bf((w1[idx] + w2[idx]) * weight[h]);
}

__launch_bounds__(256)
__global__ void fused_rms_gemm_kernel(const float* __restrict__ residual,
                                      const float* __restrict__ attn,
                                      const float* __restrict__ moe,
                                      const unsigned short* __restrict__ weff,
                                      float* __restrict__ combined,
                                      float* __restrict__ nres) {
    __shared__ unsigned short a_lds[TILE_ROWS * LDS_STRIDE];
    __shared__ float scale_lds[TILE_ROWS];

    const int t = threadIdx.x;
    const int r = t >> 2;            // local row 0..63 (4 threads per row)
    const int cb = (t & 3) * 32;     // 32-col chunk within row
    const long row0 = (long)blockIdx.x * TILE_ROWS;
    const long base = (row0 + r) * 128 + cb;

    const f32x4* resp = (const f32x4*)(residual + base);
    const f32x4* attp = (const f32x4*)(attn + base);
    const f32x4* moep = (const f32x4*)(moe + base);
    f32x4* nrp = (f32x4*)(nres + base);
    u32x2* arow = (u32x2*)(a_lds + r * LDS_STRIDE + cb);

    // Phase 1: add = residual + attn; next_residual = add + moe; sumsq; bf16(add) -> LDS
    float sumsq = 0.f;
#pragma unroll
    for (int i = 0; i < 8; ++i) {
        f32x4 a = resp[i];
        f32x4 b = attp[i];
        f32x4 m = moep[i];
        f32x4 s = a + b;
        nrp[i] = s + m;
        sumsq += s.x * s.x + s.y * s.y + s.z * s.z + s.w * s.w;
        u32x2 packed;
        packed.x = ((unsigned)f2bf(s.y) << 16) | (unsigned)f2bf(s.x);
        packed.y = ((unsigned)f2bf(s.w) << 16) | (unsigned)f2bf(s.z);
        arow[i] = packed;
    }
    sumsq += __shfl_xor(sumsq, 1);
    sumsq += __shfl_xor(sumsq, 2);
    if ((t & 3) == 0)
        scale_lds[r] = rsqrtf(sumsq * (1.0f / 128.0f) + 1e-5f);
    __syncthreads();

    // Phase 2: D[r][o] = add[r][:] . w_eff[o][:]  via mfma_f32_16x16x32_bf16
    const int w = t >> 6;       // wave 0..3, owns output cols [w*32, w*32+32)
    const int l = t & 63;
    const int lq = l >> 4;      // k-slot group 0..3
    const int lr = l & 15;      // row (A) / col (B,C) within 16

    // B frags: lane holds w_eff[o = ntile*16+lr][kk*32 + lq*8 .. +7] (same k-bijection as A)
    bf16x8 bfrag[2][4];
#pragma unroll
    for (int n = 0; n < 2; ++n) {
        const unsigned short* wp = weff + (w * 32 + n * 16 + lr) * 128 + lq * 8;
#pragma unroll
        for (int kk = 0; kk < 4; ++kk)
            bfrag[n][kk] = *(const bf16x8*)(wp + kk * 32);
    }

    f32x4 acc[4][2] = {};
#pragma unroll
    for (int rt = 0; rt < 4; ++rt) {
        const unsigned short* ap = a_lds + (rt * 16 + lr) * LDS_STRIDE + lq * 8;
#pragma unroll
        for (int kk = 0; kk < 4; ++kk) {
            bf16x8 afrag = *(const bf16x8*)(ap + kk * 32);
            acc[rt][0] = __builtin_amdgcn_mfma_f32_16x16x32_bf16(afrag, bfrag[0][kk], acc[rt][0], 0, 0, 0);
            acc[rt][1] = __builtin_amdgcn_mfma_f32_16x16x32_bf16(afrag, bfrag[1][kk], acc[rt][1], 0, 0, 0);
        }
    }

    // Epilogue: C/D layout col = lane&15, row = (lane>>4)*4 + reg  [HW-verified]
    float* cb0 = combined + row0 * 128 + w * 32 + lr;
#pragma unroll
    for (int rt = 0; rt < 4; ++rt) {
#pragma unroll
        for (int j = 0; j < 4; ++j) {
            int rr = rt * 16 + lq * 4 + j;
            float sc = scale_lds[rr];
            cb0[(long)rr * 128]      = acc[rt][0][j] * sc;
            cb0[(long)rr * 128 + 16] = acc[rt][1][j] * sc;
        }
    }
}

extern "C" void kernel_launch(void* const* d_in, const int* in_sizes, int n_in,
                              void* d_out, int out_size, void* d_ws, size_t ws_size,
                              hipStream_t stream) {
    const float* residual = (const float*)d_in[0];
    const float* attn     = (const float*)d_in[1];
    const float* moe      = (const float*)d_in[2];
    const float* weight   = (const float*)d_in[3];
    const float* w1       = (const float*)d_in[4];
    const float* w2       = (const float*)d_in[5];

    unsigned short* weff = (unsigned short*)d_ws;  // 32 KB scratch

    const int total = in_sizes[0];                 // B*S*H = 33,554,432
    const int rows = total / 128;
    float* combined = (float*)d_out;
    float* nres = combined + (size_t)total;

    prep_weights_kernel<<<64, 256, 0, stream>>>(w1, w2, weight, weff);
    fused_rms_gemm_kernel<<<rows / TILE_ROWS, 256, 0, stream>>>(
        residual, attn, moe, weff, combined, nres);
}

// Round 2
// 149.715 us; speedup vs baseline: 1.4775x; 1.4775x over previous
//
#include <hip/hip_runtime.h>
#include <hip/hip_bf16.h>

typedef float f32x4 __attribute__((ext_vector_type(4)));
typedef short bf16x8 __attribute__((ext_vector_type(8)));
typedef unsigned int u32x2 __attribute__((ext_vector_type(2)));

#define TILE_ROWS 64
#define LDS_STRIDE 136      // ushorts per A-row (272 B, 16B-aligned, non-pow2)
#define OUT_STRIDE 132      // floats per staged output row (528 B, 16B-aligned, non-pow2)

__device__ __forceinline__ unsigned short f2bf(float f) {
    union { float f; unsigned int u; } v; v.f = f;
    unsigned int u = v.u;
    u += 0x7FFFu + ((u >> 16) & 1u);   // round-to-nearest-even
    return (unsigned short)(u >> 16);
}

// w_eff[o][h] = (w1[o][h] + w2[o][h]) * weight[h], bf16, row-major [128][128]
__global__ void prep_weights_kernel(const float* __restrict__ w1,
                                    const float* __restrict__ w2,
                                    const float* __restrict__ weight,
                                    unsigned short* __restrict__ weff) {
    int idx = blockIdx.x * 256 + threadIdx.x;   // 64 blocks * 256 = 16384
    int h = idx & 127;
    weff[idx] = f2bf((w1[idx] + w2[idx]) * weight[h]);
}

__launch_bounds__(256)
__global__ void fused_rms_gemm_kernel(const float* __restrict__ residual,
                                      const float* __restrict__ attn,
                                      const float* __restrict__ moe,
                                      const unsigned short* __restrict__ weff,
                                      float* __restrict__ combined,
                                      float* __restrict__ nres) {
    // Union: phase 1/2 use bf16 A-tile [64][136]; epilogue reuses as f32 [32][132]
    __shared__ __align__(16) unsigned char smem[TILE_ROWS * LDS_STRIDE * 2]; // 17408 B
    __shared__ float scale_lds[TILE_ROWS];
    unsigned short* a_lds = (unsigned short*)smem;
    float* o_lds = (float*)smem;

    const int t = threadIdx.x;
    const int w = t >> 6;            // wave 0..3
    const int l = t & 63;
    const int half = l >> 5;         // 0/1: which of the wave's 2 rows this iter
    const int c4 = l & 31;           // f32x4 slot within a row (32 x 16B = 512B)
    const long row0 = (long)blockIdx.x * TILE_ROWS;

    // ---- Phase 1: per-instruction-contiguous loads/stores (2 x 512B segments) ----
    // wave w owns rows [w*16, w*16+16); iteration i covers rows w*16+i*2+{0,1}
#pragma unroll
    for (int i = 0; i < 8; ++i) {
        const int rloc = w * 16 + i * 2 + half;
        const long base = (row0 + rloc) * 128 + c4 * 4;
        f32x4 a = *(const f32x4*)(residual + base);
        f32x4 b = *(const f32x4*)(attn + base);
        f32x4 m = *(const f32x4*)(moe + base);
        f32x4 s = a + b;
        *(f32x4*)(nres + base) = s + m;
        float p = s.x * s.x + s.y * s.y + s.z * s.z + s.w * s.w;
        // pack bf16(add) -> LDS
        u32x2 packed;
        packed.x = ((unsigned)f2bf(s.y) << 16) | (unsigned)f2bf(s.x);
        packed.y = ((unsigned)f2bf(s.w) << 16) | (unsigned)f2bf(s.z);
        *(u32x2*)(a_lds + rloc * LDS_STRIDE + c4 * 4) = packed;
        // reduce sumsq across the 32 lanes of this row
        p += __shfl_xor(p, 1);
        p += __shfl_xor(p, 2);
        p += __shfl_xor(p, 4);
        p += __shfl_xor(p, 8);
        p += __shfl_xor(p, 16);
        if (c4 == 0)
            scale_lds[rloc] = rsqrtf(p * (1.0f / 128.0f) + 1e-5f);
    }
    __syncthreads();

    // ---- Phase 2: D[r][o] = add[r][:] . w_eff[o][:] via mfma_f32_16x16x32_bf16 ----
    const int lq = l >> 4;      // k-slot group 0..3
    const int lr = l & 15;      // row (A) / col (B,C) within 16

    // B frags: lane holds w_eff[o = w*32 + nt*16 + lr][kk*32 + lq*8 .. +7]
    bf16x8 bfrag[2][4];
#pragma unroll
    for (int n = 0; n < 2; ++n) {
        const unsigned short* wp = weff + (w * 32 + n * 16 + lr) * 128 + lq * 8;
#pragma unroll
        for (int kk = 0; kk < 4; ++kk)
            bfrag[n][kk] = *(const bf16x8*)(wp + kk * 32);
    }

    f32x4 acc[4][2] = {};
#pragma unroll
    for (int rt = 0; rt < 4; ++rt) {
        const unsigned short* ap = a_lds + (rt * 16 + lr) * LDS_STRIDE + lq * 8;
#pragma unroll
        for (int kk = 0; kk < 4; ++kk) {
            bf16x8 afrag = *(const bf16x8*)(ap + kk * 32);
            acc[rt][0] = __builtin_amdgcn_mfma_f32_16x16x32_bf16(afrag, bfrag[0][kk], acc[rt][0], 0, 0, 0);
            acc[rt][1] = __builtin_amdgcn_mfma_f32_16x16x32_bf16(afrag, bfrag[1][kk], acc[rt][1], 0, 0, 0);
        }
    }
    __syncthreads();   // all a_lds reads done; smem can be reused as o_lds

    // ---- Epilogue: stage through LDS, store combined as 1KB-contiguous f32x4 ----
    // C/D layout: col = lane&15 (=o within tile), row = lq*4 + j  [HW-verified]
#pragma unroll
    for (int h = 0; h < 2; ++h) {
#pragma unroll
        for (int rt2 = 0; rt2 < 2; ++rt2) {
            const int rt = h * 2 + rt2;
#pragma unroll
            for (int j = 0; j < 4; ++j) {
                const int rloc = rt2 * 16 + lq * 4 + j;        // row within 32-row group
                const float sc = scale_lds[h * 32 + rloc];
                o_lds[rloc * OUT_STRIDE + w * 32 + lr]      = acc[rt][0][j] * sc;
                o_lds[rloc * OUT_STRIDE + w * 32 + 16 + lr] = acc[rt][1][j] * sc;
            }
        }
        __syncthreads();
#pragma unroll
        for (int k = 0; k < 4; ++k) {
            const int c = k * 256 + t;                 // 0..1023 f32x4 chunks
            const int row = c >> 5;
            const int col = (c & 31) * 4;
            f32x4 v = *(const f32x4*)(o_lds + row * OUT_STRIDE + col);
            *(f32x4*)(combined + (row0 + h * 32 + row) * 128 + col) = v;
        }
        if (h == 0) __syncthreads();   // protect o_lds before round-1 writes
    }
}

extern "C" void kernel_launch(void* const* d_in, const int* in_sizes, int n_in,
                              void* d_out, int out_size, void* d_ws, size_t ws_size,
                              hipStream_t stream) {
    const float* residual = (const float*)d_in[0];
    const float* attn     = (const float*)d_in[1];
    const float* moe      = (const float*)d_in[2];
    const float* weight   = (const float*)d_in[3];
    const float* w1       = (const float*)d_in[4];
    const float* w2       = (const float*)d_in[5];

    unsigned short* weff = (unsigned short*)d_ws;  // 32 KB scratch

    const int total = in_sizes[0];                 // B*S*H = 33,554,432
    const int rows = total / 128;
    float* combined = (float*)d_out;
    float* nres = combined + (size_t)total;

    prep_weights_kernel<<<64, 256, 0, stream>>>(w1, w2, weff ? weight : weight, weff);
    fused_rms_gemm_kernel<<<rows / TILE_ROWS, 256, 0, stream>>>(
        residual, attn, moe, weff, combined, nres);
}